// Round 6
// baseline (2733.216 us; speedup 1.0000x reference)
//
#include <hip/hip_runtime.h>
#include <stdint.h>

// GRU fused persistent kernel, MI355X gfx950 — round 14.
// History: r8 3.47ms (MALL sc1) | r10 11.9ms (per-poll inv) | r11 2.64ms WIN
// (nt-poll XCD-local L2 exchange) | r12 3.62ms REGRESS (tag-poll BW jam) |
// r13 2.71ms NEUTRAL: consumer-side fixes (X prefetch, split-issue, 2-deep
// poll) changed nothing -> consumers have slack; the loop clock is the
// PRODUCER chain: detect -> MFMA -> LDSwrite -> barrier -> reduce+sigmoid
// -> store -> drain(~250cy) -> flag -> RTT, twice per step.
//
// r14 = shrink the detect->release chains:
//  - Phase A releases rh after computing r ONLY: 4 x@Wr (under slab
//    latency) + 12 h-MFMAs + single LDS write + single reduce+sigmoid.
//    (was: 24 h-MFMAs + double write + double reduce.)
//  - z moved ENTIRELY into the rh-RTT shadow: x@Wz + h@Uz (h frags still
//    live in regs) + x@Wh + barrier#2 + z-reduce -> zvl ready before the
//    rh poll returns. Shadow ~450cy < RTT ~600cy.
//  - X/mask(t+1) prefetch after the z-reduce, riding the rh poll (r13
//    placement; barriers drain vmcnt, so issue-points must be >=900cy
//    before the next __syncthreads -- this slot is the only one that is).
//  - Protocol, census, smoke, fallbacks: UNCHANGED from r11/r13
//    (hardware-proven). Parity LDS reuse still separated by >=3 barriers.
//
// ws (dwords): hb[2][8][8][512]=65536 | rhb[8][8][512]=32768 | hfl 8x512 |
// rfl 8x512 | census/smoke 160. Total 106656 dw = 427KB, all zeroed.

#define GT    512
#define GDIN  512
#define GDOUT 512
#define NGRP  8
#define NSL   16
#define GROWS 8
#define COLS  32
#define NWAVE 8
#define KW    64
#define NWG   (NGRP * NSL)                          // 128

#define OFF_HB    0
#define OFF_RHB   (2 * NGRP * GROWS * GDOUT)        // 65536
#define OFF_HFL   (OFF_RHB + NGRP * GROWS * GDOUT)  // 98304
#define FLSTR     4                                  // 16B per flag
#define FLGRP     (NSL * NWAVE * FLSTR)              // 512 dw per group
#define OFF_RFL   (OFF_HFL + NGRP * FLGRP)           // 102400
#define OFF_CNS   (OFF_RFL + NGRP * FLGRP)           // 106496
#define INIT_DW   (OFF_CNS + 160)                    // 106656 dw = 427KB

typedef __attribute__((ext_vector_type(8))) short bf16x8;
typedef __attribute__((ext_vector_type(4))) float f32x4;
typedef __attribute__((ext_vector_type(4))) unsigned int u32x4;

__device__ __forceinline__ short f2bf(float f) {
  union { float f; uint32_t u; } v; v.f = f;
  uint32_t r = (v.u + 0x7FFFu + ((v.u >> 16) & 1u)) >> 16;  // RNE
  return (short)(uint16_t)r;
}
__device__ __forceinline__ float bf2f(short s) {
  union { uint32_t u; float f; } v; v.u = ((uint32_t)(uint16_t)s) << 16;
  return v.f;
}
// pack f32 -> (bf16hi<<16)|bf16lo via 2x v_cvt_pk_bf16_f32
__device__ __forceinline__ uint32_t pack_hl(float v) {
  uint32_t t, o;
  asm("v_cvt_pk_bf16_f32 %0, %1, %1" : "=v"(t) : "v"(v));
  union { uint32_t u; float f; } hf; hf.u = t << 16;   // hi as f32
  float d = v - hf.f;
  asm("v_cvt_pk_bf16_f32 %0, %1, %2" : "=v"(o) : "v"(d), "v"(v));
  return o;                                            // [hi|lo]
}

__device__ __forceinline__ void st_sc1(uint32_t* p, uint32_t v) {
  asm volatile("global_store_dword %0, %1, off sc1" :: "v"(p), "v"(v) : "memory");
}
__device__ __forceinline__ void st_pl(uint32_t* p, uint32_t v) {
  asm volatile("global_store_dword %0, %1, off" :: "v"(p), "v"(v) : "memory");
}
__device__ __forceinline__ void vm_drain() {
  asm volatile("s_waitcnt vmcnt(0)" ::: "memory");
}
__device__ __forceinline__ void l1_inv() {   // one-time hygiene only (r10!)
  asm volatile("buffer_inv sc1" ::: "memory");
}
__device__ __forceinline__ uint32_t ld_nt(const uint32_t* p) {
  uint32_t v;
  asm volatile("global_load_dword %0, %1, off nt\n\ts_waitcnt vmcnt(0)"
               : "=v"(v) : "v"(p) : "memory");
  return v;
}

// issue-only slab (4x dwordx4, the wave's 16-dword A slab); wait separately
__device__ __forceinline__ void slab4_issue(const uint32_t* base, u32x4 d[4],
                                            int fast) {
  if (fast) {
    asm volatile(
      "global_load_dwordx4 %0, %4, off nt\n\t"
      "global_load_dwordx4 %1, %4, off offset:16 nt\n\t"
      "global_load_dwordx4 %2, %4, off offset:128 nt\n\t"
      "global_load_dwordx4 %3, %4, off offset:144 nt"
      : "=&v"(d[0]), "=&v"(d[1]), "=&v"(d[2]), "=&v"(d[3])
      : "v"(base) : "memory");
  } else {
    asm volatile(
      "global_load_dwordx4 %0, %4, off sc1\n\t"
      "global_load_dwordx4 %1, %4, off offset:16 sc1\n\t"
      "global_load_dwordx4 %2, %4, off offset:128 sc1\n\t"
      "global_load_dwordx4 %3, %4, off offset:144 sc1"
      : "=&v"(d[0]), "=&v"(d[1]), "=&v"(d[2]), "=&v"(d[3])
      : "v"(base) : "memory");
  }
}
__device__ __forceinline__ void slab_wait() {
  asm volatile("s_waitcnt vmcnt(0)" ::: "memory");
  __builtin_amdgcn_sched_barrier(0);     // rule #18: pin reads after waitcnt
}

// wave waits for its 2 producer WGs x 8 waves = 16 flags.
// FAST: 2-deep pipelined nt poll. SLOW: agent-scope load via MALL.
__device__ __forceinline__ void wait16(const uint32_t* fbase, uint32_t tgt,
                                       int lane, int wv, int fast, int& budget) {
  if (budget <= 0) return;
  const int idx = lane & 15;                       // lanes 16..63 duplicate
  const uint32_t* p = fbase +
      (size_t)(((2 * wv + (idx >> 3)) * NWAVE + (idx & 7)) * FLSTR);
  if (fast) {
    uint32_t v0, v1;
    asm volatile("global_load_dword %0, %1, off nt" : "=v"(v0) : "v"(p) : "memory");
    for (;;) {
      asm volatile("global_load_dword %0, %1, off nt" : "=v"(v1) : "v"(p) : "memory");
      asm volatile("s_waitcnt vmcnt(1)" ::: "memory");
      __builtin_amdgcn_sched_barrier(0);
      if (__all((int)(v0 >= tgt))) break;
      asm volatile("global_load_dword %0, %1, off nt" : "=v"(v0) : "v"(p) : "memory");
      asm volatile("s_waitcnt vmcnt(1)" ::: "memory");
      __builtin_amdgcn_sched_barrier(0);
      if (__all((int)(v1 >= tgt))) break;
      if ((budget -= 2) <= 0) break;
    }
    asm volatile("s_waitcnt vmcnt(0)" ::: "memory");  // quiesce stray poll
  } else {
    for (;;) {
      uint32_t v = __hip_atomic_load(p, __ATOMIC_RELAXED, __HIP_MEMORY_SCOPE_AGENT);
      if (__all((int)(v >= tgt))) break;
      if (--budget <= 0) break;
    }
  }
  asm volatile("" ::: "memory");
}

// 8 packed words -> hi/lo bf16x8 MFMA A-fragments (pure bit ops)
union U16x8 { uint32_t u[4]; bf16x8 v; };
__device__ __forceinline__ void mk_frags(const u32x4 A, const u32x4 B,
                                         bf16x8& hi, bf16x8& lo) {
  U16x8 h, l;
  h.u[0] = (A[0] >> 16) | (A[1] & 0xFFFF0000u);  l.u[0] = (A[0] & 0xFFFFu) | (A[1] << 16);
  h.u[1] = (A[2] >> 16) | (A[3] & 0xFFFF0000u);  l.u[1] = (A[2] & 0xFFFFu) | (A[3] << 16);
  h.u[2] = (B[0] >> 16) | (B[1] & 0xFFFF0000u);  l.u[2] = (B[0] & 0xFFFFu) | (B[1] << 16);
  h.u[3] = (B[2] >> 16) | (B[3] & 0xFFFF0000u);  l.u[3] = (B[2] & 0xFFFFu) | (B[3] << 16);
  hi = h.v; lo = l.v;
}
// f32x4 pair -> bf16x8 via 4x v_cvt_pk_bf16_f32
__device__ __forceinline__ bf16x8 cvt8(const f32x4 a, const f32x4 b) {
  U16x8 w;
  asm("v_cvt_pk_bf16_f32 %0, %1, %2" : "=v"(w.u[0]) : "v"(a[0]), "v"(a[1]));
  asm("v_cvt_pk_bf16_f32 %0, %1, %2" : "=v"(w.u[1]) : "v"(a[2]), "v"(a[3]));
  asm("v_cvt_pk_bf16_f32 %0, %1, %2" : "=v"(w.u[2]) : "v"(b[0]), "v"(b[1]));
  asm("v_cvt_pk_bf16_f32 %0, %1, %2" : "=v"(w.u[3]) : "v"(b[2]), "v"(b[3]));
  return w.v;
}

__global__ __launch_bounds__(512, 2)
void gru_fused(const float* __restrict__ X, const int* __restrict__ mask,
               const float* __restrict__ Wz, const float* __restrict__ Uz,
               const float* __restrict__ bz,
               const float* __restrict__ Wr, const float* __restrict__ Ur,
               const float* __restrict__ br,
               const float* __restrict__ Wh, const float* __restrict__ Uh,
               const float* __restrict__ bh,
               float* __restrict__ out, uint32_t* __restrict__ ws)
{
  const int tid   = threadIdx.x;
  const int wv    = tid >> 6;
  const int lane  = tid & 63;
  const int col16 = lane & 15;
  const int quad  = lane >> 4;
  const int row8  = lane & 7;

  // ---- census (assignment) + smoke test (fast/slow selection) ----
  uint32_t* cns = ws + OFF_CNS;
  __shared__ int s_mode, s_g, s_sl;
  if (tid == 0) {
    uint32_t xcc = 0;
    asm volatile("s_getreg_b32 %0, hwreg(HW_REG_XCC_ID)" : "=s"(xcc));
    xcc &= 7u;
    uint32_t slot = __hip_atomic_fetch_add(&cns[xcc], 1u, __ATOMIC_RELAXED,
                                           __HIP_MEMORY_SCOPE_AGENT);
    if (slot >= (uint32_t)NSL)
      __hip_atomic_fetch_add(&cns[9], 1u, __ATOMIC_RELAXED, __HIP_MEMORY_SCOPE_AGENT);
    __hip_atomic_fetch_add(&cns[8], 1u, __ATOMIC_RELEASE, __HIP_MEMORY_SCOPE_AGENT);
    uint32_t tv = 0; long sp = 0;
    do {
      tv = __hip_atomic_load(&cns[8], __ATOMIC_ACQUIRE, __HIP_MEMORY_SCOPE_AGENT);
    } while (tv < (uint32_t)NWG && ++sp < 2000000L);
    uint32_t bad = __hip_atomic_load(&cns[9], __ATOMIC_RELAXED, __HIP_MEMORY_SCOPE_AGENT);
    const int cok = (tv >= (uint32_t)NWG && bad == 0u);
    int g_, sl_, mode_ = 0;
    if (cok) {
      g_ = (int)xcc; sl_ = (int)slot;
      l1_inv();
      uint32_t* tok = cns + 16;
      st_pl(&tok[g_ * NSL + sl_], 1u);
      vm_drain();
      const uint32_t* np = &tok[g_ * NSL + ((sl_ + 1) & (NSL - 1))];
      int ok = 0;
      for (long i = 0; i < 300000L; ++i) {
        if (ld_nt(np) != 0u) { ok = 1; break; }
      }
      if (!ok)
        __hip_atomic_fetch_add(&cns[11], 1u, __ATOMIC_RELAXED, __HIP_MEMORY_SCOPE_AGENT);
      __hip_atomic_fetch_add(&cns[10], 1u, __ATOMIC_RELEASE, __HIP_MEMORY_SCOPE_AGENT);
      uint32_t tv2 = 0; sp = 0;
      do {
        tv2 = __hip_atomic_load(&cns[10], __ATOMIC_ACQUIRE, __HIP_MEMORY_SCOPE_AGENT);
      } while (tv2 < (uint32_t)NWG && ++sp < 2000000L);
      uint32_t fl = __hip_atomic_load(&cns[11], __ATOMIC_RELAXED, __HIP_MEMORY_SCOPE_AGENT);
      mode_ = (tv2 >= (uint32_t)NWG && fl == 0u) ? 1 : 0;
    } else {
      g_ = (int)(blockIdx.x & 7); sl_ = (int)(blockIdx.x >> 3);
    }
    s_mode = mode_; s_g = g_; s_sl = sl_;
  }
  __syncthreads();
  const int fast = __builtin_amdgcn_readfirstlane(s_mode);
  const int g    = __builtin_amdgcn_readfirstlane(s_g);
  const int sl   = __builtin_amdgcn_readfirstlane(s_sl);
  l1_inv();                            // one-time: clear cross-launch vL1

  const int jb = sl * COLS;
  const int kb = wv * KW;

  uint32_t* hb  = ws + OFF_HB;
  uint32_t* rhb = ws + OFF_RHB;
  uint32_t* hfl = ws + OFF_HFL + (size_t)g * FLGRP;
  uint32_t* rfl = ws + OFF_RFL + (size_t)g * FLGRP;
  uint32_t* hfl_my = hfl + (size_t)(sl * NWAVE + wv) * FLSTR;
  uint32_t* rfl_my = rfl + (size_t)(sl * NWAVE + wv) * FLSTR;
  uint32_t* rhg = rhb + (size_t)g * (GROWS * GDOUT);
  const int slab_off = row8 * GDOUT + kb + quad * 8;

  __shared__ __align__(16) float scrA[2][NWAVE][2][GROWS][COLS];  // 32KB
  __shared__ __align__(16) float scrB[2][NWAVE][GROWS][COLS];     // 16KB

  // ---------- one-time: weight B-fragments into registers ----------
  bf16x8 uzh[2][2], uzl[2][2], urh[2][2], url[2][2], uhh[2][2], uhl[2][2];
  bf16x8 wzf[2][2], wrf[2][2], whf[2][2];
#pragma unroll
  for (int c = 0; c < 2; ++c) {
#pragma unroll
    for (int Tt = 0; Tt < 2; ++Tt) {
      const int k0 = kb + c * 32 + quad * 8;
      const int j  = jb + Tt * 16 + col16;
      bf16x8 t_uzh, t_uzl, t_urh, t_url, t_uhh, t_uhl, t_wz, t_wr, t_wh;
#pragma unroll
      for (int i = 0; i < 8; ++i) {
        const int idx = (k0 + i) * GDOUT + j;
        float u; short hi;
        u = Uz[idx]; hi = f2bf(u); t_uzh[i] = hi; t_uzl[i] = f2bf(u - bf2f(hi));
        u = Ur[idx]; hi = f2bf(u); t_urh[i] = hi; t_url[i] = f2bf(u - bf2f(hi));
        u = Uh[idx]; hi = f2bf(u); t_uhh[i] = hi; t_uhl[i] = f2bf(u - bf2f(hi));
        t_wz[i] = f2bf(Wz[idx]);
        t_wr[i] = f2bf(Wr[idx]);
        t_wh[i] = f2bf(Wh[idx]);
      }
      uzh[c][Tt] = t_uzh; uzl[c][Tt] = t_uzl; urh[c][Tt] = t_urh; url[c][Tt] = t_url;
      uhh[c][Tt] = t_uhh; uhl[c][Tt] = t_uhl;
      wzf[c][Tt] = t_wz;  wrf[c][Tt] = t_wr;  whf[c][Tt] = t_wh;
    }
  }

  const int ecol = lane & 31;
  const float bzv = bz[jb + ecol];
  const float brv = br[jb + ecol];
  const float bhv = bh[jb + ecol];
  const int b_ep = GROWS * g + wv;

  float hreg = 0.f;
  int budget = 4000000;

  // ---- X/mask prefetch registers (t = 0) ----
  f32x4 xpA[2], xpB[2]; int mkpre;
  {
    const float* xr = X + (size_t)(GROWS * g + row8) * GT * GDIN;
#pragma unroll
    for (int c = 0; c < 2; ++c) {
      const float* xp = xr + kb + c * 32 + quad * 8;
      xpA[c] = *(const f32x4*)xp;
      xpB[c] = *(const f32x4*)(xp + 4);
    }
    mkpre = mask[(size_t)b_ep * GT + 0];
  }

  for (int t = 0; t < GT; ++t) {
    const int par = t & 1;
    // xa from prefetched regs: 8x v_cvt_pk (no vmem on critical path)
    bf16x8 xa[2];
#pragma unroll
    for (int c = 0; c < 2; ++c) xa[c] = cvt8(xpA[c], xpB[c]);
    const int mk = mkpre;

    // ==== phase A (critical): r-gate only ====
    if (t) wait16(hfl, (uint32_t)t, lane, wv, fast, budget);
    const uint32_t* hsrc = hb + ((size_t)par * NGRP + g) * (GROWS * GDOUT) + slab_off;
    u32x4 hd[4];
    slab4_issue(hsrc, hd, fast);

    f32x4 ar[2]  = {{0,0,0,0},{0,0,0,0}}, ar2[2] = {{0,0,0,0},{0,0,0,0}};
    // x@Wr overlaps the slab L2 latency (xa-only deps)
#pragma unroll
    for (int c = 0; c < 2; ++c)
#pragma unroll
      for (int Tt = 0; Tt < 2; ++Tt)
        ar2[Tt] = __builtin_amdgcn_mfma_f32_16x16x32_bf16(xa[c], wrf[c][Tt], ar2[Tt], 0, 0, 0);
    slab_wait();                          // vmcnt(0) + sched_barrier (rule #18)

    bf16x8 hhi[2], hlo[2];                // h fragments stay live for shadow-z
#pragma unroll
    for (int c = 0; c < 2; ++c) {
      mk_frags(hd[2 * c], hd[2 * c + 1], hhi[c], hlo[c]);
#pragma unroll
      for (int Tt = 0; Tt < 2; ++Tt) {
        ar[Tt]  = __builtin_amdgcn_mfma_f32_16x16x32_bf16(hhi[c], urh[c][Tt], ar[Tt],  0, 0, 0);
        ar2[Tt] = __builtin_amdgcn_mfma_f32_16x16x32_bf16(hlo[c], urh[c][Tt], ar2[Tt], 0, 0, 0);
        ar[Tt]  = __builtin_amdgcn_mfma_f32_16x16x32_bf16(hhi[c], url[c][Tt], ar[Tt],  0, 0, 0);
      }
    }

    if (quad < 2) {                       // r partials only (half of r13)
#pragma unroll
      for (int Tt = 0; Tt < 2; ++Tt)
#pragma unroll
        for (int rr = 0; rr < 4; ++rr)
          scrA[par][wv][0][quad * 4 + rr][Tt * 16 + col16] = ar[Tt][rr] + ar2[Tt][rr];
    }
    __syncthreads();                      // #1: joins all 8 waves' h-waits

    float rsum = 0.f;
#pragma unroll
    for (int w2 = 0; w2 < NWAVE; ++w2) rsum += scrA[par][w2][0][wv][ecol];
    const float rvl = 1.f / (1.f + __expf(-(rsum + brv)));
    if (lane < 32) {
      uint32_t* dst = rhg + (size_t)wv * GDOUT + jb + lane;
      const uint32_t pv = pack_hl(rvl * hreg);
      if (fast) st_pl(dst, pv); else st_sc1(dst, pv);
    }
    vm_drain();                           // rh committed at L2
    if (lane == 0) {
      if (fast) st_pl(rfl_my, (uint32_t)(t + 1)); else st_sc1(rfl_my, (uint32_t)(t + 1));
    }

    // ==== rh-RTT shadow: z-gate + x@Wh, own barrier + reduce ====
    f32x4 az[2] = {{0,0,0,0},{0,0,0,0}}, az2[2] = {{0,0,0,0},{0,0,0,0}};
    f32x4 ah[2] = {{0,0,0,0},{0,0,0,0}};
#pragma unroll
    for (int c = 0; c < 2; ++c)
#pragma unroll
      for (int Tt = 0; Tt < 2; ++Tt) {
        az2[Tt] = __builtin_amdgcn_mfma_f32_16x16x32_bf16(xa[c], wzf[c][Tt], az2[Tt], 0, 0, 0);
        az[Tt]  = __builtin_amdgcn_mfma_f32_16x16x32_bf16(hhi[c], uzh[c][Tt], az[Tt],  0, 0, 0);
        az2[Tt] = __builtin_amdgcn_mfma_f32_16x16x32_bf16(hlo[c], uzh[c][Tt], az2[Tt], 0, 0, 0);
        az[Tt]  = __builtin_amdgcn_mfma_f32_16x16x32_bf16(hhi[c], uzl[c][Tt], az[Tt],  0, 0, 0);
        ah[Tt]  = __builtin_amdgcn_mfma_f32_16x16x32_bf16(xa[c],  whf[c][Tt], ah[Tt],  0, 0, 0);
      }
    if (quad < 2) {
#pragma unroll
      for (int Tt = 0; Tt < 2; ++Tt)
#pragma unroll
        for (int rr = 0; rr < 4; ++rr)
          scrA[par][wv][1][quad * 4 + rr][Tt * 16 + col16] = az[Tt][rr] + az2[Tt][rr];
    }
    __syncthreads();                      // #2: intra-WG only, inside RTT slack

    float zsum = 0.f;
#pragma unroll
    for (int w2 = 0; w2 < NWAVE; ++w2) zsum += scrA[par][w2][1][wv][ecol];
    const float zvl = 1.f / (1.f + __expf(-(zsum + bzv)));

    // X(t+1)/mask prefetch: issued here so its latency rides the rh poll
    {
      const int tn = (t + 1 < GT) ? t + 1 : t;
      const float* xr = X + ((size_t)(GROWS * g + row8) * GT + tn) * GDIN;
#pragma unroll
      for (int c = 0; c < 2; ++c) {
        const float* xp = xr + kb + c * 32 + quad * 8;
        xpA[c] = *(const f32x4*)xp;
        xpB[c] = *(const f32x4*)(xp + 4);
      }
      mkpre = mask[(size_t)b_ep * GT + tn];
    }

    // ==== phase B (critical): candidate hh ====
    wait16(rfl, (uint32_t)(t + 1), lane, wv, fast, budget);
    u32x4 rd[4];
    slab4_issue(rhg + slab_off, rd, fast);
    slab_wait();

    f32x4 b1[2] = {{0,0,0,0},{0,0,0,0}}, b2[2] = {{0,0,0,0},{0,0,0,0}};
    f32x4 b3[2] = {{0,0,0,0},{0,0,0,0}};
#pragma unroll
    for (int c = 0; c < 2; ++c) {
      bf16x8 th, tl;
      mk_frags(rd[2 * c], rd[2 * c + 1], th, tl);
#pragma unroll
      for (int Tt = 0; Tt < 2; ++Tt) {
        b1[Tt] = __builtin_amdgcn_mfma_f32_16x16x32_bf16(th, uhh[c][Tt], b1[Tt], 0, 0, 0);
        b2[Tt] = __builtin_amdgcn_mfma_f32_16x16x32_bf16(tl, uhh[c][Tt], b2[Tt], 0, 0, 0);
        b3[Tt] = __builtin_amdgcn_mfma_f32_16x16x32_bf16(th, uhl[c][Tt], b3[Tt], 0, 0, 0);
      }
    }

    if (quad < 2) {
#pragma unroll
      for (int Tt = 0; Tt < 2; ++Tt)
#pragma unroll
        for (int rr = 0; rr < 4; ++rr)
          scrB[par][wv][quad * 4 + rr][Tt * 16 + col16] =
              ah[Tt][rr] + b1[Tt][rr] + b2[Tt][rr] + b3[Tt][rr];
    }
    __syncthreads();                      // #3: joins all 8 waves' rh-waits

    float hsum = 0.f;
#pragma unroll
    for (int w2 = 0; w2 < NWAVE; ++w2) hsum += scrB[par][w2][wv][ecol];
    const float pre = hsum + bhv;
    const float e  = __expf(2.f * pre);   // tanh, saturation-safe
    const float hh = 1.f - 2.f / (e + 1.f);
    float hn = zvl * hreg + (1.f - zvl) * hh;
    hn = (mk > 0) ? hn : hreg;
    hreg = hn;

    if (lane < 32) {
      uint32_t* hdst = hb + ((size_t)((t + 1) & 1) * NGRP + g) * (GROWS * GDOUT)
                         + (size_t)wv * GDOUT + jb + lane;
      const uint32_t pv = pack_hl(hn);
      if (fast) st_pl(hdst, pv); else st_sc1(hdst, pv);
      if (t == GT - 1) out[(size_t)b_ep * GDOUT + jb + lane] = hn;
    }
    vm_drain();                           // h committed at L2
    if (lane == 0) {
      if (fast) st_pl(hfl_my, (uint32_t)(t + 1)); else st_sc1(hfl_my, (uint32_t)(t + 1));
    }
  }
}

extern "C" void kernel_launch(void* const* d_in, const int* in_sizes, int n_in,
                              void* d_out, int out_size, void* d_ws, size_t ws_size,
                              hipStream_t stream) {
  const float* X  = (const float*)d_in[0];
  const int* mask = (const int*)d_in[1];
  const float* Wz = (const float*)d_in[2];
  const float* Uz = (const float*)d_in[3];
  const float* bz = (const float*)d_in[4];
  const float* Wr = (const float*)d_in[5];
  const float* Ur = (const float*)d_in[6];
  const float* br = (const float*)d_in[7];
  const float* Wh = (const float*)d_in[8];
  const float* Uh = (const float*)d_in[9];
  const float* bh = (const float*)d_in[10];

  hipMemsetAsync(d_ws, 0, (size_t)INIT_DW * 4, stream);

  hipLaunchKernelGGL(gru_fused, dim3(NWG), dim3(512), 0, stream,
                     X, mask, Wz, Uz, bz, Wr, Ur, br, Wh, Uh, bh,
                     (float*)d_out, (uint32_t*)d_ws);
}

// Round 7
// 2715.676 us; speedup vs baseline: 1.0065x; 1.0065x over previous
//
#include <hip/hip_runtime.h>
#include <stdint.h>

// GRU fused persistent kernel, MI355X gfx950 — round 15.
// History: r8 3.47ms (MALL sc1 flags) | r10 11.9ms (per-poll inv) | r11
// 2.64ms WIN (nt-poll, XCD-local L2 exchange) | r12 3.62ms REGRESS (64-line
// tag-poll = L2 jam) | r13 2.71 NEUTRAL (consumer-side opts: consumers have
// slack) | r14 2.73 NEUTRAL (producer MFMA-chain shaved: not the clock).
// Remaining untested critical-path segment: store -> vmcnt drain -> flag
// -> RTT. r15 removes drain AND flag entirely.
//
// r15 = SELF-TAGGED PAYLOAD LINES (no flags, no drains):
//  - 2-bit step tag (t&3) embedded in the 2 LSBs of each packed dword
//    (lo-bf16 LSBs; ~2^-14 relative noise, absmax headroom 2.5x).
//    Producer: pack|tag, ONE 128B-line store per wave, proceed. The store
//    drains under a later barrier/poll-waitcnt, off the release path.
//  - Consumer: 16-lane PROBE (1 dword per line it will read; 16 lines =
//    8 rows x 2 k-slices) until all tags match, then full slab load with
//    PER-DWORD tag verify + retry. No line/sector atomicity assumption:
//    stale sectors simply retry (rare after probe). 16 req/wave/poll vs
//    r12's 64 -> no L2 jam.
//  - Alias safety: rh line holds only t-1/t (tags differ). h is parity
//    double-buffered: slot holds t or t-2; t&3 vs (t-2)&3 differ. t=0:
//    memset zeros == exact rh(0)/h(0) payload AND tag 0 -> no special case.
//  - Overwrite safety: same all-16 joins as the flag protocol, now carried
//    by tag-polls + barriers: a WG reaches its rh(t) write only after
//    barrier#1(t) which joins 8 waves whose h(t)-polls' union = all 16 WGs,
//    each of which published h(t) only after its phase-B(t-1) rh reads
//    returned. h(t+1) overwrite of h(t-1) is >= one full step behind the
//    all-16 rh(t-1) join (barrier#3(t-1)). [r8-r14 proofs carried over.]
//  - Census + smoke unchanged (gates fast mode). Slow mode = identical tag
//    protocol with sc1 (MALL) stores/loads; correct, just slower hops.
//  - All spins budget-bounded; failures are loud (absmax), never hangs.
//
// ws (dwords): hb[2][8][8][512]=65536 | rhb[8][8][512]=32768 | cns 160.
// Total 98464 dw = 394KB, all zeroed.

#define GT    512
#define GDIN  512
#define GDOUT 512
#define NGRP  8
#define NSL   16
#define GROWS 8
#define COLS  32
#define NWAVE 8
#define KW    64
#define NWG   (NGRP * NSL)                          // 128

#define OFF_HB    0
#define OFF_RHB   (2 * NGRP * GROWS * GDOUT)        // 65536
#define OFF_CNS   (OFF_RHB + NGRP * GROWS * GDOUT)  // 98304
#define INIT_DW   (OFF_CNS + 160)                   // 98464 dw = 394KB

typedef __attribute__((ext_vector_type(8))) short bf16x8;
typedef __attribute__((ext_vector_type(4))) float f32x4;
typedef __attribute__((ext_vector_type(4))) unsigned int u32x4;

__device__ __forceinline__ short f2bf(float f) {
  union { float f; uint32_t u; } v; v.f = f;
  uint32_t r = (v.u + 0x7FFFu + ((v.u >> 16) & 1u)) >> 16;  // RNE
  return (short)(uint16_t)r;
}
__device__ __forceinline__ float bf2f(short s) {
  union { uint32_t u; float f; } v; v.u = ((uint32_t)(uint16_t)s) << 16;
  return v.f;
}
// pack f32 -> (bf16hi<<16)|bf16lo via 2x v_cvt_pk_bf16_f32
__device__ __forceinline__ uint32_t pack_hl(float v) {
  uint32_t t, o;
  asm("v_cvt_pk_bf16_f32 %0, %1, %1" : "=v"(t) : "v"(v));
  union { uint32_t u; float f; } hf; hf.u = t << 16;   // hi as f32
  float d = v - hf.f;
  asm("v_cvt_pk_bf16_f32 %0, %1, %2" : "=v"(o) : "v"(d), "v"(v));
  return o;                                            // [hi|lo]
}

__device__ __forceinline__ void st_sc1(uint32_t* p, uint32_t v) {
  asm volatile("global_store_dword %0, %1, off sc1" :: "v"(p), "v"(v) : "memory");
}
__device__ __forceinline__ void st_pl(uint32_t* p, uint32_t v) {
  asm volatile("global_store_dword %0, %1, off" :: "v"(p), "v"(v) : "memory");
}
__device__ __forceinline__ void vm_drain() {
  asm volatile("s_waitcnt vmcnt(0)" ::: "memory");
}
__device__ __forceinline__ void l1_inv() {   // one-time hygiene only (r10!)
  asm volatile("buffer_inv sc1" ::: "memory");
}
__device__ __forceinline__ uint32_t ld_nt(const uint32_t* p) {
  uint32_t v;
  asm volatile("global_load_dword %0, %1, off nt\n\ts_waitcnt vmcnt(0)"
               : "=v"(v) : "v"(p) : "memory");
  return v;
}
__device__ __forceinline__ uint32_t ld_sc1(const uint32_t* p) {
  uint32_t v;
  asm volatile("global_load_dword %0, %1, off sc1\n\ts_waitcnt vmcnt(0)"
               : "=v"(v) : "v"(p) : "memory");
  return v;
}

// issue-only slab (4x dwordx4: 16 dwords/lane, rows 0-7 x 64-wide K chunk)
__device__ __forceinline__ void slab4_issue(const uint32_t* base, u32x4 d[4],
                                            int fast) {
  if (fast) {
    asm volatile(
      "global_load_dwordx4 %0, %4, off nt\n\t"
      "global_load_dwordx4 %1, %4, off offset:16 nt\n\t"
      "global_load_dwordx4 %2, %4, off offset:128 nt\n\t"
      "global_load_dwordx4 %3, %4, off offset:144 nt"
      : "=&v"(d[0]), "=&v"(d[1]), "=&v"(d[2]), "=&v"(d[3])
      : "v"(base) : "memory");
  } else {
    asm volatile(
      "global_load_dwordx4 %0, %4, off sc1\n\t"
      "global_load_dwordx4 %1, %4, off offset:16 sc1\n\t"
      "global_load_dwordx4 %2, %4, off offset:128 sc1\n\t"
      "global_load_dwordx4 %3, %4, off offset:144 sc1"
      : "=&v"(d[0]), "=&v"(d[1]), "=&v"(d[2]), "=&v"(d[3])
      : "v"(base) : "memory");
  }
}
__device__ __forceinline__ void slab_wait() {
  asm volatile("s_waitcnt vmcnt(0)" ::: "memory");
  __builtin_amdgcn_sched_barrier(0);     // rule #18: pin reads after waitcnt
}

// probe: lanes 0-15 each watch dword0 of one of the 16 lines the wave will
// read (8 rows x 2 k-slices); spin until all carry tag tg. Upper lanes dup.
__device__ __forceinline__ void probe16(const uint32_t* kbase, uint32_t tg,
                                        int lane, int fast, int& budget) {
  if (budget <= 0) return;
  const int idx = lane & 15;
  const uint32_t* p = kbase + (size_t)(idx & 7) * GDOUT + ((idx >> 3) << 5);
  if (fast) {
    for (;;) {
      uint32_t v = ld_nt(p);
      if (__all((int)(((v ^ tg) & 3u) == 0u))) break;
      if (--budget <= 0) break;
    }
  } else {
    for (;;) {
      uint32_t v = ld_sc1(p);
      if (__all((int)(((v ^ tg) & 3u) == 0u))) break;
      if (--budget <= 0) break;
    }
  }
  asm volatile("" ::: "memory");
}
// full slab + per-dword tag verify + retry (no sector-atomicity assumption)
__device__ __forceinline__ void slab4v(const uint32_t* base, u32x4 d[4],
                                       uint32_t tg, int fast, int& budget) {
  for (;;) {
    slab4_issue(base, d, fast);
    slab_wait();
    uint32_t c = 0;
#pragma unroll
    for (int i = 0; i < 4; ++i)
      c |= (d[i][0] ^ tg) | (d[i][1] ^ tg) | (d[i][2] ^ tg) | (d[i][3] ^ tg);
    if (__all((int)((c & 3u) == 0u))) return;
    if (--budget <= 0) return;
  }
}

// 8 packed words -> hi/lo bf16x8 MFMA A-fragments (pure bit ops)
union U16x8 { uint32_t u[4]; bf16x8 v; };
__device__ __forceinline__ void mk_frags(const u32x4 A, const u32x4 B,
                                         bf16x8& hi, bf16x8& lo) {
  U16x8 h, l;
  h.u[0] = (A[0] >> 16) | (A[1] & 0xFFFF0000u);  l.u[0] = (A[0] & 0xFFFFu) | (A[1] << 16);
  h.u[1] = (A[2] >> 16) | (A[3] & 0xFFFF0000u);  l.u[1] = (A[2] & 0xFFFFu) | (A[3] << 16);
  h.u[2] = (B[0] >> 16) | (B[1] & 0xFFFF0000u);  l.u[2] = (B[0] & 0xFFFFu) | (B[1] << 16);
  h.u[3] = (B[2] >> 16) | (B[3] & 0xFFFF0000u);  l.u[3] = (B[2] & 0xFFFFu) | (B[3] << 16);
  hi = h.v; lo = l.v;
}
// f32x4 pair -> bf16x8 via 4x v_cvt_pk_bf16_f32
__device__ __forceinline__ bf16x8 cvt8(const f32x4 a, const f32x4 b) {
  U16x8 w;
  asm("v_cvt_pk_bf16_f32 %0, %1, %2" : "=v"(w.u[0]) : "v"(a[0]), "v"(a[1]));
  asm("v_cvt_pk_bf16_f32 %0, %1, %2" : "=v"(w.u[1]) : "v"(a[2]), "v"(a[3]));
  asm("v_cvt_pk_bf16_f32 %0, %1, %2" : "=v"(w.u[2]) : "v"(b[0]), "v"(b[1]));
  asm("v_cvt_pk_bf16_f32 %0, %1, %2" : "=v"(w.u[3]) : "v"(b[2]), "v"(b[3]));
  return w.v;
}

__global__ __launch_bounds__(512, 2)
void gru_fused(const float* __restrict__ X, const int* __restrict__ mask,
               const float* __restrict__ Wz, const float* __restrict__ Uz,
               const float* __restrict__ bz,
               const float* __restrict__ Wr, const float* __restrict__ Ur,
               const float* __restrict__ br,
               const float* __restrict__ Wh, const float* __restrict__ Uh,
               const float* __restrict__ bh,
               float* __restrict__ out, uint32_t* __restrict__ ws)
{
  const int tid   = threadIdx.x;
  const int wv    = tid >> 6;
  const int lane  = tid & 63;
  const int col16 = lane & 15;
  const int quad  = lane >> 4;
  const int row8  = lane & 7;

  // ---- census (assignment) + smoke test (fast/slow selection) ----
  uint32_t* cns = ws + OFF_CNS;
  __shared__ int s_mode, s_g, s_sl;
  if (tid == 0) {
    uint32_t xcc = 0;
    asm volatile("s_getreg_b32 %0, hwreg(HW_REG_XCC_ID)" : "=s"(xcc));
    xcc &= 7u;
    uint32_t slot = __hip_atomic_fetch_add(&cns[xcc], 1u, __ATOMIC_RELAXED,
                                           __HIP_MEMORY_SCOPE_AGENT);
    if (slot >= (uint32_t)NSL)
      __hip_atomic_fetch_add(&cns[9], 1u, __ATOMIC_RELAXED, __HIP_MEMORY_SCOPE_AGENT);
    __hip_atomic_fetch_add(&cns[8], 1u, __ATOMIC_RELEASE, __HIP_MEMORY_SCOPE_AGENT);
    uint32_t tv = 0; long sp = 0;
    do {
      tv = __hip_atomic_load(&cns[8], __ATOMIC_ACQUIRE, __HIP_MEMORY_SCOPE_AGENT);
    } while (tv < (uint32_t)NWG && ++sp < 2000000L);
    uint32_t bad = __hip_atomic_load(&cns[9], __ATOMIC_RELAXED, __HIP_MEMORY_SCOPE_AGENT);
    const int cok = (tv >= (uint32_t)NWG && bad == 0u);
    int g_, sl_, mode_ = 0;
    if (cok) {
      g_ = (int)xcc; sl_ = (int)slot;
      l1_inv();
      uint32_t* tok = cns + 16;
      st_pl(&tok[g_ * NSL + sl_], 1u);
      vm_drain();
      const uint32_t* np = &tok[g_ * NSL + ((sl_ + 1) & (NSL - 1))];
      int ok = 0;
      for (long i = 0; i < 300000L; ++i) {
        if (ld_nt(np) != 0u) { ok = 1; break; }
      }
      if (!ok)
        __hip_atomic_fetch_add(&cns[11], 1u, __ATOMIC_RELAXED, __HIP_MEMORY_SCOPE_AGENT);
      __hip_atomic_fetch_add(&cns[10], 1u, __ATOMIC_RELEASE, __HIP_MEMORY_SCOPE_AGENT);
      uint32_t tv2 = 0; sp = 0;
      do {
        tv2 = __hip_atomic_load(&cns[10], __ATOMIC_ACQUIRE, __HIP_MEMORY_SCOPE_AGENT);
      } while (tv2 < (uint32_t)NWG && ++sp < 2000000L);
      uint32_t fl = __hip_atomic_load(&cns[11], __ATOMIC_RELAXED, __HIP_MEMORY_SCOPE_AGENT);
      mode_ = (tv2 >= (uint32_t)NWG && fl == 0u) ? 1 : 0;
    } else {
      g_ = (int)(blockIdx.x & 7); sl_ = (int)(blockIdx.x >> 3);
    }
    s_mode = mode_; s_g = g_; s_sl = sl_;
  }
  __syncthreads();
  const int fast = __builtin_amdgcn_readfirstlane(s_mode);
  const int g    = __builtin_amdgcn_readfirstlane(s_g);
  const int sl   = __builtin_amdgcn_readfirstlane(s_sl);
  l1_inv();                            // one-time: clear cross-launch vL1

  const int jb = sl * COLS;
  const int kb = wv * KW;

  uint32_t* hb  = ws + OFF_HB;
  uint32_t* rhg = ws + OFF_RHB + (size_t)g * (GROWS * GDOUT);
  const int slab_off = row8 * GDOUT + kb + quad * 8;

  __shared__ __align__(16) float scrA[2][NWAVE][2][GROWS][COLS];  // 32KB
  __shared__ __align__(16) float scrB[2][NWAVE][GROWS][COLS];     // 16KB

  // ---------- one-time: weight B-fragments into registers ----------
  bf16x8 uzh[2][2], uzl[2][2], urh[2][2], url[2][2], uhh[2][2], uhl[2][2];
  bf16x8 wzf[2][2], wrf[2][2], whf[2][2];
#pragma unroll
  for (int c = 0; c < 2; ++c) {
#pragma unroll
    for (int Tt = 0; Tt < 2; ++Tt) {
      const int k0 = kb + c * 32 + quad * 8;
      const int j  = jb + Tt * 16 + col16;
      bf16x8 t_uzh, t_uzl, t_urh, t_url, t_uhh, t_uhl, t_wz, t_wr, t_wh;
#pragma unroll
      for (int i = 0; i < 8; ++i) {
        const int idx = (k0 + i) * GDOUT + j;
        float u; short hi;
        u = Uz[idx]; hi = f2bf(u); t_uzh[i] = hi; t_uzl[i] = f2bf(u - bf2f(hi));
        u = Ur[idx]; hi = f2bf(u); t_urh[i] = hi; t_url[i] = f2bf(u - bf2f(hi));
        u = Uh[idx]; hi = f2bf(u); t_uhh[i] = hi; t_uhl[i] = f2bf(u - bf2f(hi));
        t_wz[i] = f2bf(Wz[idx]);
        t_wr[i] = f2bf(Wr[idx]);
        t_wh[i] = f2bf(Wh[idx]);
      }
      uzh[c][Tt] = t_uzh; uzl[c][Tt] = t_uzl; urh[c][Tt] = t_urh; url[c][Tt] = t_url;
      uhh[c][Tt] = t_uhh; uhl[c][Tt] = t_uhl;
      wzf[c][Tt] = t_wz;  wrf[c][Tt] = t_wr;  whf[c][Tt] = t_wh;
    }
  }

  const int ecol = lane & 31;
  const float bzv = bz[jb + ecol];
  const float brv = br[jb + ecol];
  const float bhv = bh[jb + ecol];
  const int b_ep = GROWS * g + wv;

  float hreg = 0.f;
  int budget = 4000000;

  // ---- X/mask prefetch registers (t = 0) ----
  f32x4 xpA[2], xpB[2]; int mkpre;
  {
    const float* xr = X + (size_t)(GROWS * g + row8) * GT * GDIN;
#pragma unroll
    for (int c = 0; c < 2; ++c) {
      const float* xp = xr + kb + c * 32 + quad * 8;
      xpA[c] = *(const f32x4*)xp;
      xpB[c] = *(const f32x4*)(xp + 4);
    }
    mkpre = mask[(size_t)b_ep * GT + 0];
  }

  for (int t = 0; t < GT; ++t) {
    const int par = t & 1;
    const uint32_t tg  = (uint32_t)(t & 3);          // tag for h(t) and rh(t)
    const uint32_t tgn = (uint32_t)((t + 1) & 3);    // tag for h(t+1)
    // xa from prefetched regs: 8x v_cvt_pk (no vmem on critical path)
    bf16x8 xa[2];
#pragma unroll
    for (int c = 0; c < 2; ++c) xa[c] = cvt8(xpA[c], xpB[c]);
    const int mk = mkpre;

    // ==== phase A (critical): r-gate only ====
    f32x4 ar[2]  = {{0,0,0,0},{0,0,0,0}}, ar2[2] = {{0,0,0,0},{0,0,0,0}};
    // x@Wr before the poll: producers still working, free time
#pragma unroll
    for (int c = 0; c < 2; ++c)
#pragma unroll
      for (int Tt = 0; Tt < 2; ++Tt)
        ar2[Tt] = __builtin_amdgcn_mfma_f32_16x16x32_bf16(xa[c], wrf[c][Tt], ar2[Tt], 0, 0, 0);

    uint32_t* hslot = hb + ((size_t)par * NGRP + g) * (GROWS * GDOUT);
    probe16(hslot + kb, tg, lane, fast, budget);     // 16 lines fresh?
    u32x4 hd[4];
    slab4v(hslot + slab_off, hd, tg, fast, budget);  // load + verify + retry

    bf16x8 hhi[2], hlo[2];                // h fragments stay live for shadow-z
#pragma unroll
    for (int c = 0; c < 2; ++c) {
      mk_frags(hd[2 * c], hd[2 * c + 1], hhi[c], hlo[c]);
#pragma unroll
      for (int Tt = 0; Tt < 2; ++Tt) {
        ar[Tt]  = __builtin_amdgcn_mfma_f32_16x16x32_bf16(hhi[c], urh[c][Tt], ar[Tt],  0, 0, 0);
        ar2[Tt] = __builtin_amdgcn_mfma_f32_16x16x32_bf16(hlo[c], urh[c][Tt], ar2[Tt], 0, 0, 0);
        ar[Tt]  = __builtin_amdgcn_mfma_f32_16x16x32_bf16(hhi[c], url[c][Tt], ar[Tt],  0, 0, 0);
      }
    }

    if (quad < 2) {                       // r partials only
#pragma unroll
      for (int Tt = 0; Tt < 2; ++Tt)
#pragma unroll
        for (int rr = 0; rr < 4; ++rr)
          scrA[par][wv][0][quad * 4 + rr][Tt * 16 + col16] = ar[Tt][rr] + ar2[Tt][rr];
    }
    __syncthreads();                      // #1: joins all 8 waves' h-polls

    float rsum = 0.f;
#pragma unroll
    for (int w2 = 0; w2 < NWAVE; ++w2) rsum += scrA[par][w2][0][wv][ecol];
    const float rvl = 1.f / (1.f + __expf(-(rsum + brv)));
    if (lane < 32) {
      uint32_t* dst = rhg + (size_t)wv * GDOUT + jb + lane;
      const uint32_t pv = (pack_hl(rvl * hreg) & ~3u) | tg;
      if (fast) st_pl(dst, pv); else st_sc1(dst, pv);
    }
    // RELEASE = store issue. No drain, no flag: tag rides the payload.

    // ==== rh-RTT shadow: z-gate + x@Wh, own barrier + reduce ====
    f32x4 az[2] = {{0,0,0,0},{0,0,0,0}}, az2[2] = {{0,0,0,0},{0,0,0,0}};
    f32x4 ah[2] = {{0,0,0,0},{0,0,0,0}};
#pragma unroll
    for (int c = 0; c < 2; ++c)
#pragma unroll
      for (int Tt = 0; Tt < 2; ++Tt) {
        az2[Tt] = __builtin_amdgcn_mfma_f32_16x16x32_bf16(xa[c], wzf[c][Tt], az2[Tt], 0, 0, 0);
        az[Tt]  = __builtin_amdgcn_mfma_f32_16x16x32_bf16(hhi[c], uzh[c][Tt], az[Tt],  0, 0, 0);
        az2[Tt] = __builtin_amdgcn_mfma_f32_16x16x32_bf16(hlo[c], uzh[c][Tt], az2[Tt], 0, 0, 0);
        az[Tt]  = __builtin_amdgcn_mfma_f32_16x16x32_bf16(hhi[c], uzl[c][Tt], az[Tt],  0, 0, 0);
        ah[Tt]  = __builtin_amdgcn_mfma_f32_16x16x32_bf16(xa[c],  whf[c][Tt], ah[Tt],  0, 0, 0);
      }
    if (quad < 2) {
#pragma unroll
      for (int Tt = 0; Tt < 2; ++Tt)
#pragma unroll
        for (int rr = 0; rr < 4; ++rr)
          scrA[par][wv][1][quad * 4 + rr][Tt * 16 + col16] = az[Tt][rr] + az2[Tt][rr];
    }
    __syncthreads();                      // #2: absorbs rh-store drain (shadow)

    float zsum = 0.f;
#pragma unroll
    for (int w2 = 0; w2 < NWAVE; ++w2) zsum += scrA[par][w2][1][wv][ecol];
    const float zvl = 1.f / (1.f + __expf(-(zsum + bzv)));

    // X(t+1)/mask prefetch: latency rides the rh poll (consumer slack)
    {
      const int tn = (t + 1 < GT) ? t + 1 : t;
      const float* xr = X + ((size_t)(GROWS * g + row8) * GT + tn) * GDIN;
#pragma unroll
      for (int c = 0; c < 2; ++c) {
        const float* xp = xr + kb + c * 32 + quad * 8;
        xpA[c] = *(const f32x4*)xp;
        xpB[c] = *(const f32x4*)(xp + 4);
      }
      mkpre = mask[(size_t)b_ep * GT + tn];
    }

    // ==== phase B (critical): candidate hh ====
    probe16(rhg + kb, tg, lane, fast, budget);
    u32x4 rd[4];
    slab4v(rhg + slab_off, rd, tg, fast, budget);

    f32x4 b1[2] = {{0,0,0,0},{0,0,0,0}}, b2[2] = {{0,0,0,0},{0,0,0,0}};
    f32x4 b3[2] = {{0,0,0,0},{0,0,0,0}};
#pragma unroll
    for (int c = 0; c < 2; ++c) {
      bf16x8 th, tl;
      mk_frags(rd[2 * c], rd[2 * c + 1], th, tl);
#pragma unroll
      for (int Tt = 0; Tt < 2; ++Tt) {
        b1[Tt] = __builtin_amdgcn_mfma_f32_16x16x32_bf16(th, uhh[c][Tt], b1[Tt], 0, 0, 0);
        b2[Tt] = __builtin_amdgcn_mfma_f32_16x16x32_bf16(tl, uhh[c][Tt], b2[Tt], 0, 0, 0);
        b3[Tt] = __builtin_amdgcn_mfma_f32_16x16x32_bf16(th, uhl[c][Tt], b3[Tt], 0, 0, 0);
      }
    }

    if (quad < 2) {
#pragma unroll
      for (int Tt = 0; Tt < 2; ++Tt)
#pragma unroll
        for (int rr = 0; rr < 4; ++rr)
          scrB[par][wv][quad * 4 + rr][Tt * 16 + col16] =
              ah[Tt][rr] + b1[Tt][rr] + b2[Tt][rr] + b3[Tt][rr];
    }
    __syncthreads();                      // #3: joins all 8 waves' rh-polls

    float hsum = 0.f;
#pragma unroll
    for (int w2 = 0; w2 < NWAVE; ++w2) hsum += scrB[par][w2][wv][ecol];
    const float pre = hsum + bhv;
    const float e  = __expf(2.f * pre);   // tanh, saturation-safe
    const float hh = 1.f - 2.f / (e + 1.f);
    float hn = zvl * hreg + (1.f - zvl) * hh;
    hn = (mk > 0) ? hn : hreg;
    hreg = hn;

    if (lane < 32) {
      uint32_t* hdst = hb + ((size_t)((t + 1) & 1) * NGRP + g) * (GROWS * GDOUT)
                         + (size_t)wv * GDOUT + jb + lane;
      const uint32_t pv = (pack_hl(hn) & ~3u) | tgn;
      if (fast) st_pl(hdst, pv); else st_sc1(hdst, pv);
      if (t == GT - 1) out[(size_t)b_ep * GDOUT + jb + lane] = hn;
    }
    // RELEASE = store issue; drains under next phase-A poll/barrier.
  }
}

extern "C" void kernel_launch(void* const* d_in, const int* in_sizes, int n_in,
                              void* d_out, int out_size, void* d_ws, size_t ws_size,
                              hipStream_t stream) {
  const float* X  = (const float*)d_in[0];
  const int* mask = (const int*)d_in[1];
  const float* Wz = (const float*)d_in[2];
  const float* Uz = (const float*)d_in[3];
  const float* bz = (const float*)d_in[4];
  const float* Wr = (const float*)d_in[5];
  const float* Ur = (const float*)d_in[6];
  const float* br = (const float*)d_in[7];
  const float* Wh = (const float*)d_in[8];
  const float* Uh = (const float*)d_in[9];
  const float* bh = (const float*)d_in[10];

  // zeros == exact h(0)/rh(0) payload AND tag 0: no t=0 special case
  hipMemsetAsync(d_ws, 0, (size_t)INIT_DW * 4, stream);

  hipLaunchKernelGGL(gru_fused, dim3(NWG), dim3(512), 0, stream,
                     X, mask, Wz, Uz, bz, Wr, Ur, br, Wh, Uh, bh,
                     (float*)d_out, (uint32_t*)d_ws);
}

// Round 8
// 2572.939 us; speedup vs baseline: 1.0623x; 1.0555x over previous
//
#include <hip/hip_runtime.h>
#include <stdint.h>

// GRU fused persistent kernel, MI355X gfx950 — round 16.
// History: r8 3.47ms (MALL) | r11 2.64ms WIN (nt-poll XCD-local L2) | r12
// 3.62 REGRESS (poll BW jam) | r13/r14/r15 2.71/2.73/2.72 NEUTRAL.
// Lockstep model: period = A-chain + max(shadow, rh-vis) + B-chain + h-vis.
// r13-r15 moved work between already-full slots -> zero-sum. Two untouched
// costs: (1) __syncthreads drains vmcnt(0) -> X prefetch residual (~300-500
// cy) bites at B-slab/barriers every step; (2) shadow (z MFMA + barrier +
// z-reduce ~750cy) overflows rh-vis slack (~300-500).
//
// r16 = r15 protocol EXACTLY, with schedule-only changes:
//  - RAW BARRIERS: s_waitcnt lgkmcnt(0) + s_barrier (+sched_barrier) — LDS
//    ordering kept, vmem NOT drained. Protocol proofs never needed vmem
//    drains at barriers: read-completion is per-wave (slab4v's internal
//    vmcnt) + program order to the publish; joins unchanged.
//  - All 12 x@W MFMAs at loop top (h-vis window slack ~300cy).
//  - Shadow = 12 z h-MFMAs + LDS write only (~250cy <= rh-vis). X(t+1)
//    prefetch issued at shadow start; residual absorbed by B-probe's wait.
//  - z-reduce hidden under B-slab flight: issue slab -> raw barrier#2 ->
//    z-reduce -> slab_wait -> tag-verify (retry via slab4v if stale).
//  - Tags, census, smoke, budgets, memset: unchanged from r15.
//
// ws (dwords): hb[2][8][8][512]=65536 | rhb[8][8][512]=32768 | cns 160.
// Total 98464 dw = 394KB, all zeroed.

#define GT    512
#define GDIN  512
#define GDOUT 512
#define NGRP  8
#define NSL   16
#define GROWS 8
#define COLS  32
#define NWAVE 8
#define KW    64
#define NWG   (NGRP * NSL)                          // 128

#define OFF_HB    0
#define OFF_RHB   (2 * NGRP * GROWS * GDOUT)        // 65536
#define OFF_CNS   (OFF_RHB + NGRP * GROWS * GDOUT)  // 98304
#define INIT_DW   (OFF_CNS + 160)                   // 98464 dw = 394KB

typedef __attribute__((ext_vector_type(8))) short bf16x8;
typedef __attribute__((ext_vector_type(4))) float f32x4;
typedef __attribute__((ext_vector_type(4))) unsigned int u32x4;

__device__ __forceinline__ short f2bf(float f) {
  union { float f; uint32_t u; } v; v.f = f;
  uint32_t r = (v.u + 0x7FFFu + ((v.u >> 16) & 1u)) >> 16;  // RNE
  return (short)(uint16_t)r;
}
__device__ __forceinline__ float bf2f(short s) {
  union { uint32_t u; float f; } v; v.u = ((uint32_t)(uint16_t)s) << 16;
  return v.f;
}
// pack f32 -> (bf16hi<<16)|bf16lo via 2x v_cvt_pk_bf16_f32
__device__ __forceinline__ uint32_t pack_hl(float v) {
  uint32_t t, o;
  asm("v_cvt_pk_bf16_f32 %0, %1, %1" : "=v"(t) : "v"(v));
  union { uint32_t u; float f; } hf; hf.u = t << 16;   // hi as f32
  float d = v - hf.f;
  asm("v_cvt_pk_bf16_f32 %0, %1, %2" : "=v"(o) : "v"(d), "v"(v));
  return o;                                            // [hi|lo]
}

__device__ __forceinline__ void st_sc1(uint32_t* p, uint32_t v) {
  asm volatile("global_store_dword %0, %1, off sc1" :: "v"(p), "v"(v) : "memory");
}
__device__ __forceinline__ void st_pl(uint32_t* p, uint32_t v) {
  asm volatile("global_store_dword %0, %1, off" :: "v"(p), "v"(v) : "memory");
}
__device__ __forceinline__ void vm_drain() {
  asm volatile("s_waitcnt vmcnt(0)" ::: "memory");
}
__device__ __forceinline__ void l1_inv() {   // one-time hygiene only (r10!)
  asm volatile("buffer_inv sc1" ::: "memory");
}
// raw WG barrier: LDS ordering only; vmem loads stay in flight (the win).
__device__ __forceinline__ void wg_barrier() {
  asm volatile("s_waitcnt lgkmcnt(0)" ::: "memory");
  __builtin_amdgcn_s_barrier();
  __builtin_amdgcn_sched_barrier(0);
}
__device__ __forceinline__ uint32_t ld_nt(const uint32_t* p) {
  uint32_t v;
  asm volatile("global_load_dword %0, %1, off nt\n\ts_waitcnt vmcnt(0)"
               : "=v"(v) : "v"(p) : "memory");
  return v;
}
__device__ __forceinline__ uint32_t ld_sc1(const uint32_t* p) {
  uint32_t v;
  asm volatile("global_load_dword %0, %1, off sc1\n\ts_waitcnt vmcnt(0)"
               : "=v"(v) : "v"(p) : "memory");
  return v;
}

// issue-only slab (4x dwordx4: 16 dwords/lane, rows 0-7 x 64-wide K chunk)
__device__ __forceinline__ void slab4_issue(const uint32_t* base, u32x4 d[4],
                                            int fast) {
  if (fast) {
    asm volatile(
      "global_load_dwordx4 %0, %4, off nt\n\t"
      "global_load_dwordx4 %1, %4, off offset:16 nt\n\t"
      "global_load_dwordx4 %2, %4, off offset:128 nt\n\t"
      "global_load_dwordx4 %3, %4, off offset:144 nt"
      : "=&v"(d[0]), "=&v"(d[1]), "=&v"(d[2]), "=&v"(d[3])
      : "v"(base) : "memory");
  } else {
    asm volatile(
      "global_load_dwordx4 %0, %4, off sc1\n\t"
      "global_load_dwordx4 %1, %4, off offset:16 sc1\n\t"
      "global_load_dwordx4 %2, %4, off offset:128 sc1\n\t"
      "global_load_dwordx4 %3, %4, off offset:144 sc1"
      : "=&v"(d[0]), "=&v"(d[1]), "=&v"(d[2]), "=&v"(d[3])
      : "v"(base) : "memory");
  }
}
__device__ __forceinline__ void slab_wait() {
  asm volatile("s_waitcnt vmcnt(0)" ::: "memory");
  __builtin_amdgcn_sched_barrier(0);     // rule #18: pin reads after waitcnt
}

// probe: lanes 0-15 each watch dword0 of one of the 16 lines the wave will
// read (8 rows x 2 k-slices); spin until all carry tag tg. Upper lanes dup.
__device__ __forceinline__ void probe16(const uint32_t* kbase, uint32_t tg,
                                        int lane, int fast, int& budget) {
  if (budget <= 0) return;
  const int idx = lane & 15;
  const uint32_t* p = kbase + (size_t)(idx & 7) * GDOUT + ((idx >> 3) << 5);
  if (fast) {
    for (;;) {
      uint32_t v = ld_nt(p);
      if (__all((int)(((v ^ tg) & 3u) == 0u))) break;
      if (--budget <= 0) break;
    }
  } else {
    for (;;) {
      uint32_t v = ld_sc1(p);
      if (__all((int)(((v ^ tg) & 3u) == 0u))) break;
      if (--budget <= 0) break;
    }
  }
  asm volatile("" ::: "memory");
}
// full slab + per-dword tag verify + retry (no sector-atomicity assumption)
__device__ __forceinline__ void slab4v(const uint32_t* base, u32x4 d[4],
                                       uint32_t tg, int fast, int& budget) {
  for (;;) {
    slab4_issue(base, d, fast);
    slab_wait();
    uint32_t c = 0;
#pragma unroll
    for (int i = 0; i < 4; ++i)
      c |= (d[i][0] ^ tg) | (d[i][1] ^ tg) | (d[i][2] ^ tg) | (d[i][3] ^ tg);
    if (__all((int)((c & 3u) == 0u))) return;
    if (--budget <= 0) return;
  }
}

// 8 packed words -> hi/lo bf16x8 MFMA A-fragments (pure bit ops)
union U16x8 { uint32_t u[4]; bf16x8 v; };
__device__ __forceinline__ void mk_frags(const u32x4 A, const u32x4 B,
                                         bf16x8& hi, bf16x8& lo) {
  U16x8 h, l;
  h.u[0] = (A[0] >> 16) | (A[1] & 0xFFFF0000u);  l.u[0] = (A[0] & 0xFFFFu) | (A[1] << 16);
  h.u[1] = (A[2] >> 16) | (A[3] & 0xFFFF0000u);  l.u[1] = (A[2] & 0xFFFFu) | (A[3] << 16);
  h.u[2] = (B[0] >> 16) | (B[1] & 0xFFFF0000u);  l.u[2] = (B[0] & 0xFFFFu) | (B[1] << 16);
  h.u[3] = (B[2] >> 16) | (B[3] & 0xFFFF0000u);  l.u[3] = (B[2] & 0xFFFFu) | (B[3] << 16);
  hi = h.v; lo = l.v;
}
// f32x4 pair -> bf16x8 via 4x v_cvt_pk_bf16_f32
__device__ __forceinline__ bf16x8 cvt8(const f32x4 a, const f32x4 b) {
  U16x8 w;
  asm("v_cvt_pk_bf16_f32 %0, %1, %2" : "=v"(w.u[0]) : "v"(a[0]), "v"(a[1]));
  asm("v_cvt_pk_bf16_f32 %0, %1, %2" : "=v"(w.u[1]) : "v"(a[2]), "v"(a[3]));
  asm("v_cvt_pk_bf16_f32 %0, %1, %2" : "=v"(w.u[2]) : "v"(b[0]), "v"(b[1]));
  asm("v_cvt_pk_bf16_f32 %0, %1, %2" : "=v"(w.u[3]) : "v"(b[2]), "v"(b[3]));
  return w.v;
}

__global__ __launch_bounds__(512, 2)
void gru_fused(const float* __restrict__ X, const int* __restrict__ mask,
               const float* __restrict__ Wz, const float* __restrict__ Uz,
               const float* __restrict__ bz,
               const float* __restrict__ Wr, const float* __restrict__ Ur,
               const float* __restrict__ br,
               const float* __restrict__ Wh, const float* __restrict__ Uh,
               const float* __restrict__ bh,
               float* __restrict__ out, uint32_t* __restrict__ ws)
{
  const int tid   = threadIdx.x;
  const int wv    = tid >> 6;
  const int lane  = tid & 63;
  const int col16 = lane & 15;
  const int quad  = lane >> 4;
  const int row8  = lane & 7;

  // ---- census (assignment) + smoke test (fast/slow selection) ----
  uint32_t* cns = ws + OFF_CNS;
  __shared__ int s_mode, s_g, s_sl;
  if (tid == 0) {
    uint32_t xcc = 0;
    asm volatile("s_getreg_b32 %0, hwreg(HW_REG_XCC_ID)" : "=s"(xcc));
    xcc &= 7u;
    uint32_t slot = __hip_atomic_fetch_add(&cns[xcc], 1u, __ATOMIC_RELAXED,
                                           __HIP_MEMORY_SCOPE_AGENT);
    if (slot >= (uint32_t)NSL)
      __hip_atomic_fetch_add(&cns[9], 1u, __ATOMIC_RELAXED, __HIP_MEMORY_SCOPE_AGENT);
    __hip_atomic_fetch_add(&cns[8], 1u, __ATOMIC_RELEASE, __HIP_MEMORY_SCOPE_AGENT);
    uint32_t tv = 0; long sp = 0;
    do {
      tv = __hip_atomic_load(&cns[8], __ATOMIC_ACQUIRE, __HIP_MEMORY_SCOPE_AGENT);
    } while (tv < (uint32_t)NWG && ++sp < 2000000L);
    uint32_t bad = __hip_atomic_load(&cns[9], __ATOMIC_RELAXED, __HIP_MEMORY_SCOPE_AGENT);
    const int cok = (tv >= (uint32_t)NWG && bad == 0u);
    int g_, sl_, mode_ = 0;
    if (cok) {
      g_ = (int)xcc; sl_ = (int)slot;
      l1_inv();
      uint32_t* tok = cns + 16;
      st_pl(&tok[g_ * NSL + sl_], 1u);
      vm_drain();
      const uint32_t* np = &tok[g_ * NSL + ((sl_ + 1) & (NSL - 1))];
      int ok = 0;
      for (long i = 0; i < 300000L; ++i) {
        if (ld_nt(np) != 0u) { ok = 1; break; }
      }
      if (!ok)
        __hip_atomic_fetch_add(&cns[11], 1u, __ATOMIC_RELAXED, __HIP_MEMORY_SCOPE_AGENT);
      __hip_atomic_fetch_add(&cns[10], 1u, __ATOMIC_RELEASE, __HIP_MEMORY_SCOPE_AGENT);
      uint32_t tv2 = 0; sp = 0;
      do {
        tv2 = __hip_atomic_load(&cns[10], __ATOMIC_ACQUIRE, __HIP_MEMORY_SCOPE_AGENT);
      } while (tv2 < (uint32_t)NWG && ++sp < 2000000L);
      uint32_t fl = __hip_atomic_load(&cns[11], __ATOMIC_RELAXED, __HIP_MEMORY_SCOPE_AGENT);
      mode_ = (tv2 >= (uint32_t)NWG && fl == 0u) ? 1 : 0;
    } else {
      g_ = (int)(blockIdx.x & 7); sl_ = (int)(blockIdx.x >> 3);
    }
    s_mode = mode_; s_g = g_; s_sl = sl_;
  }
  __syncthreads();
  const int fast = __builtin_amdgcn_readfirstlane(s_mode);
  const int g    = __builtin_amdgcn_readfirstlane(s_g);
  const int sl   = __builtin_amdgcn_readfirstlane(s_sl);
  l1_inv();                            // one-time: clear cross-launch vL1

  const int jb = sl * COLS;
  const int kb = wv * KW;

  uint32_t* hb  = ws + OFF_HB;
  uint32_t* rhg = ws + OFF_RHB + (size_t)g * (GROWS * GDOUT);
  const int slab_off = row8 * GDOUT + kb + quad * 8;

  __shared__ __align__(16) float scrA[2][NWAVE][2][GROWS][COLS];  // 32KB
  __shared__ __align__(16) float scrB[2][NWAVE][GROWS][COLS];     // 16KB

  // ---------- one-time: weight B-fragments into registers ----------
  bf16x8 uzh[2][2], uzl[2][2], urh[2][2], url[2][2], uhh[2][2], uhl[2][2];
  bf16x8 wzf[2][2], wrf[2][2], whf[2][2];
#pragma unroll
  for (int c = 0; c < 2; ++c) {
#pragma unroll
    for (int Tt = 0; Tt < 2; ++Tt) {
      const int k0 = kb + c * 32 + quad * 8;
      const int j  = jb + Tt * 16 + col16;
      bf16x8 t_uzh, t_uzl, t_urh, t_url, t_uhh, t_uhl, t_wz, t_wr, t_wh;
#pragma unroll
      for (int i = 0; i < 8; ++i) {
        const int idx = (k0 + i) * GDOUT + j;
        float u; short hi;
        u = Uz[idx]; hi = f2bf(u); t_uzh[i] = hi; t_uzl[i] = f2bf(u - bf2f(hi));
        u = Ur[idx]; hi = f2bf(u); t_urh[i] = hi; t_url[i] = f2bf(u - bf2f(hi));
        u = Uh[idx]; hi = f2bf(u); t_uhh[i] = hi; t_uhl[i] = f2bf(u - bf2f(hi));
        t_wz[i] = f2bf(Wz[idx]);
        t_wr[i] = f2bf(Wr[idx]);
        t_wh[i] = f2bf(Wh[idx]);
      }
      uzh[c][Tt] = t_uzh; uzl[c][Tt] = t_uzl; urh[c][Tt] = t_urh; url[c][Tt] = t_url;
      uhh[c][Tt] = t_uhh; uhl[c][Tt] = t_uhl;
      wzf[c][Tt] = t_wz;  wrf[c][Tt] = t_wr;  whf[c][Tt] = t_wh;
    }
  }

  const int ecol = lane & 31;
  const float bzv = bz[jb + ecol];
  const float brv = br[jb + ecol];
  const float bhv = bh[jb + ecol];
  const int b_ep = GROWS * g + wv;

  float hreg = 0.f;
  int budget = 4000000;

  // ---- X/mask prefetch registers (t = 0) ----
  f32x4 xpA[2], xpB[2]; int mkpre;
  {
    const float* xr = X + (size_t)(GROWS * g + row8) * GT * GDIN;
#pragma unroll
    for (int c = 0; c < 2; ++c) {
      const float* xp = xr + kb + c * 32 + quad * 8;
      xpA[c] = *(const f32x4*)xp;
      xpB[c] = *(const f32x4*)(xp + 4);
    }
    mkpre = mask[(size_t)b_ep * GT + 0];
  }

  for (int t = 0; t < GT; ++t) {
    const int par = t & 1;
    const uint32_t tg  = (uint32_t)(t & 3);          // tag for h(t) and rh(t)
    const uint32_t tgn = (uint32_t)((t + 1) & 3);    // tag for h(t+1)

    // ==== h-vis window: xa cvt + ALL 12 x@W MFMAs ====
    bf16x8 xa[2];
#pragma unroll
    for (int c = 0; c < 2; ++c) xa[c] = cvt8(xpA[c], xpB[c]);
    const int mk = mkpre;

    f32x4 ar2[2] = {{0,0,0,0},{0,0,0,0}};
    f32x4 az2[2] = {{0,0,0,0},{0,0,0,0}};
    f32x4 ah[2]  = {{0,0,0,0},{0,0,0,0}};
#pragma unroll
    for (int c = 0; c < 2; ++c)
#pragma unroll
      for (int Tt = 0; Tt < 2; ++Tt) {
        ar2[Tt] = __builtin_amdgcn_mfma_f32_16x16x32_bf16(xa[c], wrf[c][Tt], ar2[Tt], 0, 0, 0);
        az2[Tt] = __builtin_amdgcn_mfma_f32_16x16x32_bf16(xa[c], wzf[c][Tt], az2[Tt], 0, 0, 0);
        ah[Tt]  = __builtin_amdgcn_mfma_f32_16x16x32_bf16(xa[c], whf[c][Tt], ah[Tt],  0, 0, 0);
      }

    // ==== phase A (critical): r-gate ====
    uint32_t* hslot = hb + ((size_t)par * NGRP + g) * (GROWS * GDOUT);
    probe16(hslot + kb, tg, lane, fast, budget);     // 16 lines fresh?
    u32x4 hd[4];
    slab4v(hslot + slab_off, hd, tg, fast, budget);  // load + verify + retry

    f32x4 ar[2] = {{0,0,0,0},{0,0,0,0}};
    bf16x8 hhi[2], hlo[2];                // h fragments stay live for shadow-z
#pragma unroll
    for (int c = 0; c < 2; ++c) {
      mk_frags(hd[2 * c], hd[2 * c + 1], hhi[c], hlo[c]);
#pragma unroll
      for (int Tt = 0; Tt < 2; ++Tt) {
        ar[Tt]  = __builtin_amdgcn_mfma_f32_16x16x32_bf16(hhi[c], urh[c][Tt], ar[Tt],  0, 0, 0);
        ar2[Tt] = __builtin_amdgcn_mfma_f32_16x16x32_bf16(hlo[c], urh[c][Tt], ar2[Tt], 0, 0, 0);
        ar[Tt]  = __builtin_amdgcn_mfma_f32_16x16x32_bf16(hhi[c], url[c][Tt], ar[Tt],  0, 0, 0);
      }
    }

    if (quad < 2) {                       // r partials only
#pragma unroll
      for (int Tt = 0; Tt < 2; ++Tt)
#pragma unroll
        for (int rr = 0; rr < 4; ++rr)
          scrA[par][wv][0][quad * 4 + rr][Tt * 16 + col16] = ar[Tt][rr] + ar2[Tt][rr];
    }
    wg_barrier();                         // #1 (raw): joins all 8 waves' h-polls

    float rsum = 0.f;
#pragma unroll
    for (int w2 = 0; w2 < NWAVE; ++w2) rsum += scrA[par][w2][0][wv][ecol];
    const float rvl = 1.f / (1.f + __expf(-(rsum + brv)));
    if (lane < 32) {
      uint32_t* dst = rhg + (size_t)wv * GDOUT + jb + lane;
      const uint32_t pv = (pack_hl(rvl * hreg) & ~3u) | tg;
      if (fast) st_pl(dst, pv); else st_sc1(dst, pv);
    }
    // RELEASE = store issue (tag rides the payload).

    // ==== shadow (<= rh-vis): X prefetch issue + 12 z h-MFMAs + LDS ====
    {
      const int tn = (t + 1 < GT) ? t + 1 : t;
      const float* xr = X + ((size_t)(GROWS * g + row8) * GT + tn) * GDIN;
#pragma unroll
      for (int c = 0; c < 2; ++c) {
        const float* xp = xr + kb + c * 32 + quad * 8;
        xpA[c] = *(const f32x4*)xp;
        xpB[c] = *(const f32x4*)(xp + 4);
      }
      mkpre = mask[(size_t)b_ep * GT + tn];
    }
    f32x4 az[2] = {{0,0,0,0},{0,0,0,0}};
#pragma unroll
    for (int c = 0; c < 2; ++c)
#pragma unroll
      for (int Tt = 0; Tt < 2; ++Tt) {
        az[Tt]  = __builtin_amdgcn_mfma_f32_16x16x32_bf16(hhi[c], uzh[c][Tt], az[Tt],  0, 0, 0);
        az2[Tt] = __builtin_amdgcn_mfma_f32_16x16x32_bf16(hlo[c], uzh[c][Tt], az2[Tt], 0, 0, 0);
        az[Tt]  = __builtin_amdgcn_mfma_f32_16x16x32_bf16(hhi[c], uzl[c][Tt], az[Tt],  0, 0, 0);
      }
    if (quad < 2) {
#pragma unroll
      for (int Tt = 0; Tt < 2; ++Tt)
#pragma unroll
        for (int rr = 0; rr < 4; ++rr)
          scrA[par][wv][1][quad * 4 + rr][Tt * 16 + col16] = az[Tt][rr] + az2[Tt][rr];
    }

    // ==== phase B (critical): candidate hh ====
    probe16(rhg + kb, tg, lane, fast, budget);       // absorbs X residual too
    u32x4 rd[4];
    slab4_issue(rhg + slab_off, rd, fast);           // slab flies...
    wg_barrier();                         // #2 (raw): joins z-partial writes
    float zsum = 0.f;                     // ...z-reduce hidden under slab
#pragma unroll
    for (int w2 = 0; w2 < NWAVE; ++w2) zsum += scrA[par][w2][1][wv][ecol];
    const float zvl = 1.f / (1.f + __expf(-(zsum + bzv)));
    slab_wait();
    {
      uint32_t c = 0;
#pragma unroll
      for (int i = 0; i < 4; ++i)
        c |= (rd[i][0] ^ tg) | (rd[i][1] ^ tg) | (rd[i][2] ^ tg) | (rd[i][3] ^ tg);
      if (!__all((int)((c & 3u) == 0u)))
        slab4v(rhg + slab_off, rd, tg, fast, budget);  // rare stale-sector retry
    }

    f32x4 b1[2] = {{0,0,0,0},{0,0,0,0}}, b2[2] = {{0,0,0,0},{0,0,0,0}};
    f32x4 b3[2] = {{0,0,0,0},{0,0,0,0}};
#pragma unroll
    for (int c = 0; c < 2; ++c) {
      bf16x8 th, tl;
      mk_frags(rd[2 * c], rd[2 * c + 1], th, tl);
#pragma unroll
      for (int Tt = 0; Tt < 2; ++Tt) {
        b1[Tt] = __builtin_amdgcn_mfma_f32_16x16x32_bf16(th, uhh[c][Tt], b1[Tt], 0, 0, 0);
        b2[Tt] = __builtin_amdgcn_mfma_f32_16x16x32_bf16(tl, uhh[c][Tt], b2[Tt], 0, 0, 0);
        b3[Tt] = __builtin_amdgcn_mfma_f32_16x16x32_bf16(th, uhl[c][Tt], b3[Tt], 0, 0, 0);
      }
    }

    if (quad < 2) {
#pragma unroll
      for (int Tt = 0; Tt < 2; ++Tt)
#pragma unroll
        for (int rr = 0; rr < 4; ++rr)
          scrB[par][wv][quad * 4 + rr][Tt * 16 + col16] =
              ah[Tt][rr] + b1[Tt][rr] + b2[Tt][rr] + b3[Tt][rr];
    }
    wg_barrier();                         // #3 (raw): joins all 8 waves' rh-polls

    float hsum = 0.f;
#pragma unroll
    for (int w2 = 0; w2 < NWAVE; ++w2) hsum += scrB[par][w2][wv][ecol];
    const float pre = hsum + bhv;
    const float e  = __expf(2.f * pre);   // tanh, saturation-safe
    const float hh = 1.f - 2.f / (e + 1.f);
    float hn = zvl * hreg + (1.f - zvl) * hh;
    hn = (mk > 0) ? hn : hreg;
    hreg = hn;

    if (lane < 32) {
      uint32_t* hdst = hb + ((size_t)((t + 1) & 1) * NGRP + g) * (GROWS * GDOUT)
                         + (size_t)wv * GDOUT + jb + lane;
      const uint32_t pv = (pack_hl(hn) & ~3u) | tgn;
      if (fast) st_pl(hdst, pv); else st_sc1(hdst, pv);
      if (t == GT - 1) out[(size_t)b_ep * GDOUT + jb + lane] = hn;
    }
    // RELEASE = store issue; drains under next phase-A poll.
  }
}

extern "C" void kernel_launch(void* const* d_in, const int* in_sizes, int n_in,
                              void* d_out, int out_size, void* d_ws, size_t ws_size,
                              hipStream_t stream) {
  const float* X  = (const float*)d_in[0];
  const int* mask = (const int*)d_in[1];
  const float* Wz = (const float*)d_in[2];
  const float* Uz = (const float*)d_in[3];
  const float* bz = (const float*)d_in[4];
  const float* Wr = (const float*)d_in[5];
  const float* Ur = (const float*)d_in[6];
  const float* br = (const float*)d_in[7];
  const float* Wh = (const float*)d_in[8];
  const float* Uh = (const float*)d_in[9];
  const float* bh = (const float*)d_in[10];

  // zeros == exact h(0)/rh(0) payload AND tag 0: no t=0 special case
  hipMemsetAsync(d_ws, 0, (size_t)INIT_DW * 4, stream);

  hipLaunchKernelGGL(gru_fused, dim3(NWG), dim3(512), 0, stream,
                     X, mask, Wz, Uz, bz, Wr, Ur, br, Wh, Uh, bh,
                     (float*)d_out, (uint32_t*)d_ws);
}